// Round 1
// baseline (2998.447 us; speedup 1.0000x reference)
//
#include <hip/hip_runtime.h>
#include <hip/hip_bf16.h>
#include <math.h>

#define S_    2048
#define HID_  4096
#define HQ_   32
#define HKV_  8
#define D_    128
#define G_    4
#define OBS_  128
#define W_    32
#define NKV_  1024
#define NQ_   4096
#define SCALE_ 0.08838834764831845f
// K_KEEP = ceil(0.3*128) = 39; threshold index = D - K_KEEP = 89
#define THR_IDX_ 89

typedef __attribute__((ext_vector_type(4))) float f32x4;
typedef __attribute__((ext_vector_type(8))) short s16x8;
typedef __attribute__((ext_vector_type(8))) unsigned short u16x8;
typedef __attribute__((ext_vector_type(4))) unsigned short u16x4;
typedef unsigned short ushort_t;

__device__ __forceinline__ unsigned short f2bf(float x) {
  union { float f; unsigned u; } v; v.f = x;
  unsigned r = v.u + 0x7FFFu + ((v.u >> 16) & 1u);
  return (unsigned short)(r >> 16);
}

// ---------------- fp32 GEMM: C(M=2048 x N) = A(2048 x 4096) @ B(4096 x N) ----------------
__global__ __launch_bounds__(256) void gemm_f32(const float* __restrict__ A,
                                                const float* __restrict__ Bw,
                                                float* __restrict__ C, int N) {
  __shared__ float a_t[16][136];  // [k][m]
  __shared__ float b_t[16][136];  // [k][n]
  const int t  = threadIdx.x;
  const int tx = t & 15, ty = t >> 4;
  const int bm = blockIdx.y, bn = blockIdx.x;
  float acc[8][8];
#pragma unroll
  for (int i = 0; i < 8; i++)
#pragma unroll
    for (int j = 0; j < 8; j++) acc[i][j] = 0.f;

  for (int kb = 0; kb < HID_ / 16; ++kb) {
    __syncthreads();
#pragma unroll
    for (int u = 0; u < 2; ++u) {
      int idx = t * 2 + u;
      int r = idx >> 2, c4 = idx & 3;
      float4 va = *(const float4*)(A + (size_t)(bm * 128 + r) * HID_ + kb * 16 + c4 * 4);
      a_t[c4 * 4 + 0][r] = va.x; a_t[c4 * 4 + 1][r] = va.y;
      a_t[c4 * 4 + 2][r] = va.z; a_t[c4 * 4 + 3][r] = va.w;
      int rb = idx >> 5, cb = idx & 31;
      float4 vb = *(const float4*)(Bw + (size_t)(kb * 16 + rb) * N + bn * 128 + cb * 4);
      *(float4*)&b_t[rb][cb * 4] = vb;
    }
    __syncthreads();
#pragma unroll
    for (int kk = 0; kk < 16; ++kk) {
      float a0[8], b0[8];
      *(float4*)&a0[0] = *(const float4*)&a_t[kk][ty * 8];
      *(float4*)&a0[4] = *(const float4*)&a_t[kk][ty * 8 + 4];
      *(float4*)&b0[0] = *(const float4*)&b_t[kk][tx * 8];
      *(float4*)&b0[4] = *(const float4*)&b_t[kk][tx * 8 + 4];
#pragma unroll
      for (int i = 0; i < 8; i++)
#pragma unroll
        for (int j = 0; j < 8; j++) acc[i][j] = fmaf(a0[i], b0[j], acc[i][j]);
    }
  }
#pragma unroll
  for (int i = 0; i < 8; i++) {
    float* cp = C + (size_t)(bm * 128 + ty * 8 + i) * N + bn * 128 + tx * 8;
    *(float4*)cp = *(float4*)&acc[i][0];
    *(float4*)(cp + 4) = *(float4*)&acc[i][4];
  }
}

// ---------------- inv_freq table (correctly-rounded f32 from double) ----------------
__global__ void freq_kernel(float* __restrict__ invf) {
  int j = threadIdx.x;
  if (j < 64) invf[j] = (float)(1.0 / pow(500000.0, (double)j / 64.0));
}

// ---------------- RoPE (in place on f32, optional bf16 copy) ----------------
__global__ void rope_kernel(float* __restrict__ X, ushort_t* __restrict__ Xb,
                            const float* __restrict__ invf, int H, int total) {
  int idx = blockIdx.x * 256 + threadIdx.x;
  if (idx >= total) return;
  int j = idx & 63;
  int h = (idx >> 6) % H;
  int s = idx / (64 * H);
  float inv = invf[j];
  float ang = (float)s * inv;
  float sn, cs;
  sincosf(ang, &sn, &cs);
  size_t base = (size_t)s * (H * D_) + h * D_ + j;
  float x1 = X[base], x2 = X[base + 64];
  float o1 = x1 * cs - x2 * sn;
  float o2 = x2 * cs + x1 * sn;
  X[base] = o1; X[base + 64] = o2;
  if (Xb) { Xb[base] = f2bf(o1); Xb[base + 64] = f2bf(o2); }
}

// ---------------- observation attention -> w_obs[h][i][j] ----------------
__global__ __launch_bounds__(256) void obs_kernel(const float* __restrict__ qf,
                                                  const float* __restrict__ kf,
                                                  float* __restrict__ wobs) {
  const int h = blockIdx.x >> 7;
  const int i = blockIdx.x & 127;
  const int t = threadIdx.x;
  const int jmax = S_ - OBS_ + i;  // inclusive causal bound; also the query position
  __shared__ float qrow[G_][D_];
  __shared__ float srow[G_][S_];
  __shared__ float red[256];
  if (t < D_) {
#pragma unroll
    for (int g = 0; g < G_; ++g)
      qrow[g][t] = qf[(size_t)jmax * NQ_ + (h * G_ + g) * D_ + t];
  }
  __syncthreads();
  float sm0 = -INFINITY, sm1 = -INFINITY, sm2 = -INFINITY, sm3 = -INFINITY;
  for (int j = t; j <= jmax; j += 256) {
    const float4* kp = (const float4*)(kf + (size_t)j * NKV_ + h * D_);
    float a0 = 0.f, a1 = 0.f, a2 = 0.f, a3 = 0.f;
#pragma unroll
    for (int d4 = 0; d4 < 32; ++d4) {
      float4 kv = kp[d4];
      a0 += qrow[0][d4 * 4 + 0] * kv.x + qrow[0][d4 * 4 + 1] * kv.y +
            qrow[0][d4 * 4 + 2] * kv.z + qrow[0][d4 * 4 + 3] * kv.w;
      a1 += qrow[1][d4 * 4 + 0] * kv.x + qrow[1][d4 * 4 + 1] * kv.y +
            qrow[1][d4 * 4 + 2] * kv.z + qrow[1][d4 * 4 + 3] * kv.w;
      a2 += qrow[2][d4 * 4 + 0] * kv.x + qrow[2][d4 * 4 + 1] * kv.y +
            qrow[2][d4 * 4 + 2] * kv.z + qrow[2][d4 * 4 + 3] * kv.w;
      a3 += qrow[3][d4 * 4 + 0] * kv.x + qrow[3][d4 * 4 + 1] * kv.y +
            qrow[3][d4 * 4 + 2] * kv.z + qrow[3][d4 * 4 + 3] * kv.w;
    }
    a0 *= SCALE_; a1 *= SCALE_; a2 *= SCALE_; a3 *= SCALE_;
    srow[0][j] = a0; srow[1][j] = a1; srow[2][j] = a2; srow[3][j] = a3;
    sm0 = fmaxf(sm0, a0); sm1 = fmaxf(sm1, a1); sm2 = fmaxf(sm2, a2); sm3 = fmaxf(sm3, a3);
  }
  float smg[4] = {sm0, sm1, sm2, sm3};
  float rd[4];
#pragma unroll
  for (int g = 0; g < 4; ++g) {
    red[t] = smg[g]; __syncthreads();
    for (int off = 128; off > 0; off >>= 1) {
      if (t < off) red[t] = fmaxf(red[t], red[t + off]);
      __syncthreads();
    }
    float mx = red[0]; __syncthreads();
    float ssum = 0.f;
    for (int j = t; j <= jmax; j += 256) {
      float p = expf(srow[g][j] - mx);
      srow[g][j] = p;
      ssum += p;
    }
    red[t] = ssum; __syncthreads();
    for (int off = 128; off > 0; off >>= 1) {
      if (t < off) red[t] += red[t + off];
      __syncthreads();
    }
    rd[g] = 1.0f / red[0]; __syncthreads();
  }
  for (int j = t; j < S_; j += 256) {
    float v = 0.f;
    if (j <= jmax)
      v = (srow[0][j] * rd[0] + srow[1][j] * rd[1] + srow[2][j] * rd[2] + srow[3][j] * rd[3]) * 0.25f;
    wobs[(size_t)(h * OBS_ + i) * S_ + j] = v;
  }
}

// ---------------- imp[h][j] = sum_i w_obs / counts ----------------
__global__ void imp_kernel(const float* __restrict__ wobs, float* __restrict__ imp) {
  int idx = blockIdx.x * 256 + threadIdx.x;
  if (idx >= HKV_ * S_) return;
  int h = idx >> 11;
  int j = idx & 2047;
  float s = 0.f;
  for (int i = 0; i < OBS_; ++i) s += wobs[(size_t)(h * OBS_ + i) * S_ + j];
  float cnt = (float)min(OBS_, S_ - j);
  imp[idx] = s / cnt;
}

// ---------------- global sort + quantile thresholds ----------------
__global__ __launch_bounds__(1024) void sort_kernel(const float* __restrict__ imp,
                                                    float* __restrict__ thr) {
  __shared__ float a[16384];
  const int t = threadIdx.x;
  const int NC = HKV_ * (S_ - W_);  // 16128
#pragma unroll
  for (int m = 0; m < 16; ++m) {
    int idx = m * 1024 + t;
    float v;
    if (idx < NC) { int h = idx / (S_ - W_); int j = idx % (S_ - W_); v = imp[h * S_ + j]; }
    else v = INFINITY;
    a[idx] = v;
  }
  for (int k = 2; k <= 16384; k <<= 1) {
    for (int j = k >> 1; j > 0; j >>= 1) {
      __syncthreads();
#pragma unroll
      for (int m = 0; m < 16; ++m) {
        int i = m * 1024 + t;
        int l = i ^ j;
        if (l > i) {
          float x = a[i], y = a[l];
          bool up = ((i & k) == 0);
          if (up ? (x > y) : (x < y)) { a[i] = y; a[l] = x; }
        }
      }
    }
  }
  __syncthreads();
  if (t == 0) {
    double ph = 0.95 * (double)(NC - 1);
    int lh = (int)ph; double fh = ph - (double)lh;
    double th = (double)a[lh] + ((double)a[lh + 1] - (double)a[lh]) * fh;
    double pl = 0.2 * (double)(NC - 1);
    int ll = (int)pl; double fl = pl - (double)ll;
    double tl = (double)a[ll] + ((double)a[ll + 1] - (double)a[ll]) * fl;
    thr[0] = (float)th;
    thr[1] = (float)tl;
  }
}

// ---------------- levels + top-k sparsify K,V -> bf16; eviction bias ----------------
__global__ __launch_bounds__(128) void sparsify_kernel(const float* __restrict__ kf,
                                                       const float* __restrict__ vf,
                                                       const float* __restrict__ imp,
                                                       const float* __restrict__ thr,
                                                       ushort_t* __restrict__ ksp,
                                                       ushort_t* __restrict__ vsp,
                                                       float* __restrict__ ebias) {
  const int b = blockIdx.x;
  const int j = b >> 3;
  const int h = b & 7;
  const int t = threadIdx.x;
  float ipv = imp[h * S_ + j];
  bool dense = (j >= S_ - W_) || (j < 2);
  int lvl = dense ? 0 : ((ipv >= thr[0]) ? 0 : ((ipv < thr[1]) ? 2 : 1));
  if (t == 0) ebias[h * S_ + j] = (lvl == 2) ? -INFINITY : 0.0f;
  __shared__ float av[128];
  __shared__ float thv;
  size_t base = (size_t)j * NKV_ + h * D_;
  // K
  float kvv = kf[base + t];
  av[t] = fabsf(kvv);
  __syncthreads();
  {
    float at = av[t]; int cnt = 0;
    for (int m = 0; m < 128; ++m) { float am = av[m]; cnt += (am < at) || (am == at && m < t); }
    if (cnt == THR_IDX_) thv = at;
  }
  __syncthreads();
  {
    bool keep = (lvl == 0) || (lvl == 1 && fabsf(kvv) >= thv);
    ksp[base + t] = f2bf(keep ? kvv : 0.0f);
  }
  __syncthreads();
  // V
  float vvv = vf[base + t];
  av[t] = fabsf(vvv);
  __syncthreads();
  {
    float at = av[t]; int cnt = 0;
    for (int m = 0; m < 128; ++m) { float am = av[m]; cnt += (am < at) || (am == at && m < t); }
    if (cnt == THR_IDX_) thv = at;
  }
  __syncthreads();
  {
    bool keep = (lvl == 0) || (lvl == 1 && fabsf(vvv) >= thv);
    vsp[base + t] = f2bf(keep ? vvv : 0.0f);
  }
}

// ---------------- cast wo -> bf16 ----------------
__global__ void castbf_kernel(const float* __restrict__ src, ushort_t* __restrict__ dst, int n4) {
  int idx = blockIdx.x * 256 + threadIdx.x;
  if (idx >= n4) return;
  float4 v = ((const float4*)src)[idx];
  u16x4 o;
  o[0] = f2bf(v.x); o[1] = f2bf(v.y); o[2] = f2bf(v.z); o[3] = f2bf(v.w);
  *(u16x4*)(dst + (size_t)idx * 4) = o;
}

// ---------------- main causal sparse attention (bf16 MFMA, flash-style) ----------------
__global__ __launch_bounds__(256) void attn_kernel(const ushort_t* __restrict__ qbp,
                                                   const ushort_t* __restrict__ ksp,
                                                   const ushort_t* __restrict__ vsp,
                                                   const float* __restrict__ ebias,
                                                   ushort_t* __restrict__ ob16) {
  __shared__ ushort_t k_lds[32][136];
  __shared__ ushort_t v_ldsT[128][40];
  __shared__ ushort_t p_lds[4][16][40];
  const int h = blockIdx.y;
  const int hk = h >> 2;
  const int qb = blockIdx.x;
  const int t = threadIdx.x;
  const int wave = t >> 6;
  const int lane = t & 63;
  const int lc = lane & 15;
  const int lg = lane >> 4;
  const int q0 = qb * 64 + wave * 16;

  s16x8 qfrag[4];
#pragma unroll
  for (int db = 0; db < 4; ++db)
    qfrag[db] = *(const s16x8*)(qbp + (size_t)(q0 + lc) * NQ_ + h * D_ + db * 32 + lg * 8);

  f32x4 o[8];
#pragma unroll
  for (int n = 0; n < 8; ++n) o[n] = 0.f;
  float mrow[4] = {-INFINITY, -INFINITY, -INFINITY, -INFINITY};
  float lrow[4] = {0.f, 0.f, 0.f, 0.f};

  const int ntiles = 2 * qb + 2;
  for (int tile = 0; tile < ntiles; ++tile) {
    const int j0 = tile * 32;
    __syncthreads();
#pragma unroll
    for (int u = 0; u < 2; ++u) {
      int idx = t * 2 + u;
      int jj = idx >> 4;
      int du = (idx & 15) * 8;
      u16x8 kv8 = *(const u16x8*)(ksp + (size_t)(j0 + jj) * NKV_ + hk * D_ + du);
      *(u16x8*)&k_lds[jj][du] = kv8;
      u16x8 vv8 = *(const u16x8*)(vsp + (size_t)(j0 + jj) * NKV_ + hk * D_ + du);
#pragma unroll
      for (int e = 0; e < 8; ++e) v_ldsT[du + e][jj] = vv8[e];
    }
    __syncthreads();

    f32x4 sfr0 = 0.f, sfr1 = 0.f;
#pragma unroll
    for (int db = 0; db < 4; ++db) {
      s16x8 kf0 = *(const s16x8*)&k_lds[lc][db * 32 + lg * 8];
      s16x8 kf1 = *(const s16x8*)&k_lds[16 + lc][db * 32 + lg * 8];
      sfr0 = __builtin_amdgcn_mfma_f32_16x16x32_bf16(qfrag[db], kf0, sfr0, 0, 0, 0);
      sfr1 = __builtin_amdgcn_mfma_f32_16x16x32_bf16(qfrag[db], kf1, sfr1, 0, 0, 0);
    }
    float eb0 = ebias[hk * S_ + j0 + lc];
    float eb1 = ebias[hk * S_ + j0 + 16 + lc];
    float p0[4], p1[4], scl[4];
#pragma unroll
    for (int r = 0; r < 4; ++r) {
      int row = q0 + lg * 4 + r;
      float s0 = (j0 + lc <= row) ? sfr0[r] * SCALE_ + eb0 : -INFINITY;
      float s1 = (j0 + 16 + lc <= row) ? sfr1[r] * SCALE_ + eb1 : -INFINITY;
      float tm = fmaxf(s0, s1);
#pragma unroll
      for (int off = 1; off < 16; off <<= 1) tm = fmaxf(tm, __shfl_xor(tm, off, 64));
      float mnew = fmaxf(mrow[r], tm);
      float sc_ = expf(mrow[r] - mnew);
      float e0 = expf(s0 - mnew);
      float e1 = expf(s1 - mnew);
      float ps = e0 + e1;
#pragma unroll
      for (int off = 1; off < 16; off <<= 1) ps += __shfl_xor(ps, off, 64);
      lrow[r] = lrow[r] * sc_ + ps;
      mrow[r] = mnew;
      scl[r] = sc_;
      p0[r] = e0; p1[r] = e1;
    }
#pragma unroll
    for (int n = 0; n < 8; ++n) {
      f32x4 ov = o[n];
#pragma unroll
      for (int r = 0; r < 4; ++r) ov[r] *= scl[r];
      o[n] = ov;
    }
#pragma unroll
    for (int r = 0; r < 4; ++r) {
      p_lds[wave][lg * 4 + r][lc] = f2bf(p0[r]);
      p_lds[wave][lg * 4 + r][16 + lc] = f2bf(p1[r]);
    }
    asm volatile("s_waitcnt lgkmcnt(0)" ::: "memory");
    s16x8 pa = *(const s16x8*)&p_lds[wave][lc][lg * 8];
#pragma unroll
    for (int n = 0; n < 8; ++n) {
      s16x8 vfrag = *(const s16x8*)&v_ldsT[n * 16 + lc][lg * 8];
      o[n] = __builtin_amdgcn_mfma_f32_16x16x32_bf16(pa, vfrag, o[n], 0, 0, 0);
    }
  }
#pragma unroll
  for (int r = 0; r < 4; ++r) {
    float rinv = 1.0f / lrow[r];
    int row = q0 + lg * 4 + r;
#pragma unroll
    for (int n = 0; n < 8; ++n)
      ob16[(size_t)row * NQ_ + h * D_ + n * 16 + lc] = f2bf(o[n][r] * rinv);
  }
}

// ---------------- out projection: out(2048x4096) = o_bf16 @ wo_bf16 ----------------
__global__ __launch_bounds__(256) void outproj_kernel(const ushort_t* __restrict__ ob16,
                                                      const ushort_t* __restrict__ wob16,
                                                      float* __restrict__ C) {
  __shared__ ushort_t a_lds[128][40];
  __shared__ ushort_t b_ldsT[128][40];
  const int t = threadIdx.x;
  const int bm = blockIdx.y, bn = blockIdx.x;
  const int wave = t >> 6, lane = t & 63;
  const int lc = lane & 15, lg = lane >> 4;
  const int wm = wave >> 1, wn = wave & 1;
  f32x4 acc[4][4];
#pragma unroll
  for (int fi = 0; fi < 4; ++fi)
#pragma unroll
    for (int fj = 0; fj < 4; ++fj) acc[fi][fj] = 0.f;

  for (int kb = 0; kb < HID_ / 32; ++kb) {
    __syncthreads();
#pragma unroll
    for (int u = 0; u < 2; ++u) {
      int idx = t * 2 + u;
      int r = idx >> 2, ca = (idx & 3) * 8;
      u16x8 va = *(const u16x8*)(ob16 + (size_t)(bm * 128 + r) * NQ_ + kb * 32 + ca);
      *(u16x8*)&a_lds[r][ca] = va;
      int rb = idx >> 4, cb = (idx & 15) * 8;
      u16x8 vb = *(const u16x8*)(wob16 + (size_t)(kb * 32 + rb) * HID_ + bn * 128 + cb);
#pragma unroll
      for (int e = 0; e < 8; ++e) b_ldsT[cb + e][rb] = vb[e];
    }
    __syncthreads();
    s16x8 af[4], bg[4];
#pragma unroll
    for (int f = 0; f < 4; ++f) {
      af[f] = *(const s16x8*)&a_lds[wm * 64 + f * 16 + lc][lg * 8];
      bg[f] = *(const s16x8*)&b_ldsT[wn * 64 + f * 16 + lc][lg * 8];
    }
#pragma unroll
    for (int fi = 0; fi < 4; ++fi)
#pragma unroll
      for (int fj = 0; fj < 4; ++fj)
        acc[fi][fj] = __builtin_amdgcn_mfma_f32_16x16x32_bf16(af[fi], bg[fj], acc[fi][fj], 0, 0, 0);
  }
#pragma unroll
  for (int fi = 0; fi < 4; ++fi)
#pragma unroll
    for (int fj = 0; fj < 4; ++fj)
#pragma unroll
      for (int r = 0; r < 4; ++r)
        C[(size_t)(bm * 128 + wm * 64 + fi * 16 + lg * 4 + r) * HID_ +
          bn * 128 + wn * 64 + fj * 16 + lc] = acc[fi][fj][r];
}

// ---------------- launcher ----------------
extern "C" void kernel_launch(void* const* d_in, const int* in_sizes, int n_in,
                              void* d_out, int out_size, void* d_ws, size_t ws_size,
                              hipStream_t stream) {
  (void)in_sizes; (void)n_in; (void)out_size; (void)ws_size;
  const float* hid = (const float*)d_in[0];
  const float* wq  = (const float*)d_in[1];
  const float* wk  = (const float*)d_in[2];
  const float* wv  = (const float*)d_in[3];
  const float* wo  = (const float*)d_in[4];
  float* out = (float*)d_out;
  char* ws = (char*)d_ws;
  size_t off = 0;
  auto alloc = [&](size_t bytes) -> void* {
    void* p = ws + off;
    off += (bytes + 255) & ~(size_t)255;
    return p;
  };
  float*    qf    = (float*)alloc((size_t)S_ * NQ_ * 4);
  float*    kf    = (float*)alloc((size_t)S_ * NKV_ * 4);
  float*    vf    = (float*)alloc((size_t)S_ * NKV_ * 4);
  ushort_t* qb16  = (ushort_t*)alloc((size_t)S_ * NQ_ * 2);
  ushort_t* ksp   = (ushort_t*)alloc((size_t)S_ * NKV_ * 2);
  ushort_t* vsp   = (ushort_t*)alloc((size_t)S_ * NKV_ * 2);
  ushort_t* ob16  = (ushort_t*)alloc((size_t)S_ * NQ_ * 2);
  ushort_t* wob16 = (ushort_t*)alloc((size_t)NQ_ * HID_ * 2);
  float*    wobs  = (float*)alloc((size_t)HKV_ * OBS_ * S_ * 4);
  float*    impv  = (float*)alloc((size_t)HKV_ * S_ * 4);
  float*    eb    = (float*)alloc((size_t)HKV_ * S_ * 4);
  float*    invf  = (float*)alloc(256);
  float*    thr   = (float*)alloc(256);

  gemm_f32<<<dim3(NQ_ / 128, S_ / 128), 256, 0, stream>>>(hid, wq, qf, NQ_);
  gemm_f32<<<dim3(NKV_ / 128, S_ / 128), 256, 0, stream>>>(hid, wk, kf, NKV_);
  gemm_f32<<<dim3(NKV_ / 128, S_ / 128), 256, 0, stream>>>(hid, wv, vf, NKV_);
  freq_kernel<<<1, 64, 0, stream>>>(invf);
  rope_kernel<<<(S_ * HQ_ * 64 + 255) / 256, 256, 0, stream>>>(qf, qb16, invf, HQ_, S_ * HQ_ * 64);
  rope_kernel<<<(S_ * HKV_ * 64 + 255) / 256, 256, 0, stream>>>(kf, nullptr, invf, HKV_, S_ * HKV_ * 64);
  obs_kernel<<<HKV_ * OBS_, 256, 0, stream>>>(qf, kf, wobs);
  imp_kernel<<<(HKV_ * S_ + 255) / 256, 256, 0, stream>>>(wobs, impv);
  sort_kernel<<<1, 1024, 0, stream>>>(impv, thr);
  sparsify_kernel<<<S_ * HKV_, 128, 0, stream>>>(kf, vf, impv, thr, ksp, vsp, eb);
  castbf_kernel<<<((NQ_ * HID_ / 4) + 255) / 256, 256, 0, stream>>>(wo, wob16, NQ_ * HID_ / 4);
  attn_kernel<<<dim3(S_ / 64, HQ_), 256, 0, stream>>>(qb16, ksp, vsp, eb, ob16);
  outproj_kernel<<<dim3(HID_ / 128, S_ / 128), 256, 0, stream>>>(ob16, wob16, out);
}

// Round 2
// 1311.023 us; speedup vs baseline: 2.2871x; 2.2871x over previous
//
#include <hip/hip_runtime.h>
#include <hip/hip_bf16.h>
#include <math.h>

#define S_    2048
#define HID_  4096
#define HQ_   32
#define HKV_  8
#define D_    128
#define G_    4
#define OBS_  128
#define W_    32
#define NKV_  1024
#define NQ_   4096
#define KLD_  2048
#define SCALE_ 0.08838834764831845f
#define THR_IDX_ 89
#define NC_   16128

typedef __attribute__((ext_vector_type(4))) float f32x4;
typedef __attribute__((ext_vector_type(8))) short s16x8;
typedef __attribute__((ext_vector_type(8))) unsigned short u16x8;
typedef __attribute__((ext_vector_type(4))) unsigned short u16x4;
typedef unsigned short ushort_t;

__device__ __forceinline__ unsigned short f2bf(float x) {
  union { float f; unsigned u; } v; v.f = x;
  unsigned r = v.u + 0x7FFFu + ((v.u >> 16) & 1u);
  return (unsigned short)(r >> 16);
}
__device__ __forceinline__ float bf2f(unsigned short b) {
  union { unsigned u; float f; } v; v.u = ((unsigned)b) << 16;
  return v.f;
}
__device__ __forceinline__ void gload_lds16(const void* g, void* l) {
  __builtin_amdgcn_global_load_lds((const __attribute__((address_space(1))) unsigned int*)g,
                                   (__attribute__((address_space(3))) unsigned int*)l, 16, 0, 0);
}

// ---------------- split fp32 -> 3 bf16 terms (elementwise, row-major kept) ----------------
__global__ __launch_bounds__(256) void split3_kernel(const float* __restrict__ src,
                                                     ushort_t* __restrict__ d0,
                                                     ushort_t* __restrict__ d1,
                                                     ushort_t* __restrict__ d2, int n4) {
  int idx = blockIdx.x * 256 + threadIdx.x;
  if (idx >= n4) return;
  float4 v = ((const float4*)src)[idx];
  u16x4 o0, o1, o2;
  float xs[4] = {v.x, v.y, v.z, v.w};
#pragma unroll
  for (int e = 0; e < 4; ++e) {
    float x = xs[e];
    unsigned short b0 = f2bf(x);
    float r = x - bf2f(b0);
    unsigned short b1 = f2bf(r);
    float r2 = r - bf2f(b1);
    unsigned short b2 = f2bf(r2);
    o0[e] = b0; o1[e] = b1; o2[e] = b2;
  }
  *(u16x4*)(d0 + (size_t)idx * 4) = o0;
  *(u16x4*)(d1 + (size_t)idx * 4) = o1;
  *(u16x4*)(d2 + (size_t)idx * 4) = o2;
}

// ---------------- split + transpose weights: (4096 x N fp32) -> up to 3x (N x 4096 bf16) ----------------
__global__ __launch_bounds__(256) void splitT_kernel(const float* __restrict__ src, int N,
                                                     ushort_t* __restrict__ t0,
                                                     ushort_t* __restrict__ t1,
                                                     ushort_t* __restrict__ t2) {
  __shared__ float tile[64][65];
  const int t = threadIdx.x;
  const int n0 = blockIdx.x * 64, k0 = blockIdx.y * 64;
#pragma unroll
  for (int i = 0; i < 16; ++i) {
    int idx = i * 256 + t;
    int r = idx >> 6, c = idx & 63;
    tile[r][c] = src[(size_t)(k0 + r) * N + n0 + c];
  }
  __syncthreads();
#pragma unroll
  for (int i = 0; i < 16; ++i) {
    int idx = i * 256 + t;
    int n = idx >> 6, kk = idx & 63;
    float x = tile[kk][n];
    unsigned short b0 = f2bf(x);
    size_t o = (size_t)(n0 + n) * HID_ + k0 + kk;
    t0[o] = b0;
    if (t1) {
      float r = x - bf2f(b0);
      unsigned short b1 = f2bf(r);
      t1[o] = b1;
      float r2 = r - bf2f(b1);
      t2[o] = f2bf(r2);
    }
  }
}

// ---------------- unified bf16 MFMA GEMM (A: MxK rows, B: NxK rows = B^T), C: MxN fp32 ----
// MODE 0: C = A0*B0^T
// MODE 1: C = A0B0 + A0B1 + A1B0 + A1B1
// MODE 2: C += A0B1 + A1B0
template<int MODE>
__global__ __launch_bounds__(256) void gemm_bt(const ushort_t* __restrict__ A0,
                                               const ushort_t* __restrict__ A1,
                                               const ushort_t* __restrict__ B0,
                                               const ushort_t* __restrict__ B1,
                                               float* __restrict__ C,
                                               int M, int N, int K) {
  constexpr int NT = (MODE == 0) ? 2 : 4;
  __shared__ ushort_t lds[NT * 128 * 64];
  const int t = threadIdx.x;
  const int wave = t >> 6, lane = t & 63;
  const int lc = lane & 15, lg = lane >> 4;
  const int bm = blockIdx.y, bn = blockIdx.x;
  const int wm = wave >> 1, wn = wave & 1;
  const int srow = t >> 3;      // row within 32-row group-block
  const int schunk = t & 7;     // 16B chunk within 128B row

  f32x4 acc[4][4];
#pragma unroll
  for (int fi = 0; fi < 4; ++fi)
#pragma unroll
    for (int fj = 0; fj < 4; ++fj) acc[fi][fj] = 0.f;

  for (int kb = 0; kb < K / 64; ++kb) {
    __syncthreads();
#pragma unroll
    for (int tid = 0; tid < NT; ++tid) {
      const ushort_t* src = (tid == 0) ? A0 : (tid == 1) ? B0 : (tid == 2) ? A1 : B1;
      const int rb = (tid == 0 || tid == 2) ? bm : bn;
#pragma unroll
      for (int g = 0; g < 4; ++g) {
        int row = g * 32 + srow;
        int sw = schunk ^ (row & 7);
        const ushort_t* gp = src + (size_t)(rb * 128 + row) * K + kb * 64 + sw * 8;
        ushort_t* lp = lds + tid * 8192 + g * 2048 + wave * 512;
        gload_lds16(gp, lp);
      }
    }
    __syncthreads();
#pragma unroll
    for (int ks = 0; ks < 2; ++ks) {
      s16x8 a0f[4], b0f[4], a1f[4], b1f[4];
#pragma unroll
      for (int f = 0; f < 4; ++f) {
        int ra = wm * 64 + f * 16 + lc;
        int ca = ((ks * 4 + lg) ^ (ra & 7)) * 8;
        a0f[f] = *(const s16x8*)(lds + 0 * 8192 + ra * 64 + ca);
        int rb2 = wn * 64 + f * 16 + lc;
        int cb = ((ks * 4 + lg) ^ (rb2 & 7)) * 8;
        b0f[f] = *(const s16x8*)(lds + 1 * 8192 + rb2 * 64 + cb);
        if constexpr (MODE >= 1) {
          a1f[f] = *(const s16x8*)(lds + 2 * 8192 + ra * 64 + ca);
          b1f[f] = *(const s16x8*)(lds + 3 * 8192 + rb2 * 64 + cb);
        }
      }
#pragma unroll
      for (int fi = 0; fi < 4; ++fi)
#pragma unroll
        for (int fj = 0; fj < 4; ++fj) {
          if constexpr (MODE == 0) {
            acc[fi][fj] = __builtin_amdgcn_mfma_f32_16x16x32_bf16(a0f[fi], b0f[fj], acc[fi][fj], 0, 0, 0);
          } else if constexpr (MODE == 1) {
            acc[fi][fj] = __builtin_amdgcn_mfma_f32_16x16x32_bf16(a0f[fi], b0f[fj], acc[fi][fj], 0, 0, 0);
            acc[fi][fj] = __builtin_amdgcn_mfma_f32_16x16x32_bf16(a0f[fi], b1f[fj], acc[fi][fj], 0, 0, 0);
            acc[fi][fj] = __builtin_amdgcn_mfma_f32_16x16x32_bf16(a1f[fi], b0f[fj], acc[fi][fj], 0, 0, 0);
            acc[fi][fj] = __builtin_amdgcn_mfma_f32_16x16x32_bf16(a1f[fi], b1f[fj], acc[fi][fj], 0, 0, 0);
          } else {
            acc[fi][fj] = __builtin_amdgcn_mfma_f32_16x16x32_bf16(a0f[fi], b1f[fj], acc[fi][fj], 0, 0, 0);
            acc[fi][fj] = __builtin_amdgcn_mfma_f32_16x16x32_bf16(a1f[fi], b0f[fj], acc[fi][fj], 0, 0, 0);
          }
        }
    }
  }
#pragma unroll
  for (int fi = 0; fi < 4; ++fi)
#pragma unroll
    for (int fj = 0; fj < 4; ++fj)
#pragma unroll
      for (int r = 0; r < 4; ++r) {
        size_t o = (size_t)(bm * 128 + wm * 64 + fi * 16 + lg * 4 + r) * N +
                   bn * 128 + wn * 64 + fj * 16 + lc;
        if constexpr (MODE == 2) C[o] += acc[fi][fj][r];
        else C[o] = acc[fi][fj][r];
      }
}

// ---------------- fp32 obs-Q GEMM, K-split into 16 partials (exact fp32 decision path) ----
__global__ __launch_bounds__(256) void gemm_obsq(const float* __restrict__ A,
                                                 const float* __restrict__ Bw,
                                                 float* __restrict__ Cp) {
  __shared__ float a_t[16][136];
  __shared__ float b_t[16][136];
  const int t = threadIdx.x, tx = t & 15, ty = t >> 4;
  const int bn = blockIdx.x, z = blockIdx.z;
  float acc[8][8];
#pragma unroll
  for (int i = 0; i < 8; i++)
#pragma unroll
    for (int j = 0; j < 8; j++) acc[i][j] = 0.f;
  for (int kb = z * 16; kb < z * 16 + 16; ++kb) {
    __syncthreads();
#pragma unroll
    for (int u = 0; u < 2; ++u) {
      int idx = t * 2 + u;
      int r = idx >> 2, c4 = idx & 3;
      float4 va = *(const float4*)(A + (size_t)r * HID_ + kb * 16 + c4 * 4);
      a_t[c4 * 4 + 0][r] = va.x; a_t[c4 * 4 + 1][r] = va.y;
      a_t[c4 * 4 + 2][r] = va.z; a_t[c4 * 4 + 3][r] = va.w;
      int rb = idx >> 5, cb = idx & 31;
      float4 vb = *(const float4*)(Bw + (size_t)(kb * 16 + rb) * NQ_ + bn * 128 + cb * 4);
      *(float4*)&b_t[rb][cb * 4] = vb;
    }
    __syncthreads();
#pragma unroll
    for (int kk = 0; kk < 16; ++kk) {
      float a0[8], b0[8];
      *(float4*)&a0[0] = *(const float4*)&a_t[kk][ty * 8];
      *(float4*)&a0[4] = *(const float4*)&a_t[kk][ty * 8 + 4];
      *(float4*)&b0[0] = *(const float4*)&b_t[kk][tx * 8];
      *(float4*)&b0[4] = *(const float4*)&b_t[kk][tx * 8 + 4];
#pragma unroll
      for (int i = 0; i < 8; i++)
#pragma unroll
        for (int j = 0; j < 8; j++) acc[i][j] = fmaf(a0[i], b0[j], acc[i][j]);
    }
  }
  float* cp0 = Cp + (size_t)z * 128 * NQ_;
#pragma unroll
  for (int i = 0; i < 8; i++) {
    float* cp = cp0 + (size_t)(ty * 8 + i) * NQ_ + bn * 128 + tx * 8;
    *(float4*)cp = *(float4*)&acc[i][0];
    *(float4*)(cp + 4) = *(float4*)&acc[i][4];
  }
}

__global__ void reduce16_kernel(const float* __restrict__ Cp, float* __restrict__ out, int n) {
  int idx = blockIdx.x * 256 + threadIdx.x;
  if (idx >= n) return;
  float s = 0.f;
#pragma unroll
  for (int z = 0; z < 16; ++z) s += Cp[(size_t)z * n + idx];
  out[idx] = s;
}

// ---------------- inv_freq ----------------
__global__ void freq_kernel(float* __restrict__ invf) {
  int j = threadIdx.x;
  if (j < 64) invf[j] = (float)(1.0 / pow(500000.0, (double)j / 64.0));
}

// ---------------- RoPE (fp32 in place, optional bf16 out); ld = row stride ----------------
__global__ void rope_kernel(float* __restrict__ X, ushort_t* __restrict__ Xb,
                            const float* __restrict__ invf, int H, int ld, int pos0, int total) {
  int idx = blockIdx.x * 256 + threadIdx.x;
  if (idx >= total) return;
  int j = idx & 63;
  int h = (idx >> 6) % H;
  int s = idx / (64 * H);
  float ang = (float)(pos0 + s) * invf[j];
  float sn, cs;
  sincosf(ang, &sn, &cs);
  size_t base = (size_t)s * ld + h * D_ + j;
  float x1 = X[base], x2 = X[base + 64];
  float o1 = x1 * cs - x2 * sn;
  float o2 = x2 * cs + x1 * sn;
  X[base] = o1; X[base + 64] = o2;
  if (Xb) { Xb[base] = f2bf(o1); Xb[base + 64] = f2bf(o2); }
}

// ---------------- observation attention -> w_obs[h][i][j] ----------------
__global__ __launch_bounds__(256) void obs_kernel(const float* __restrict__ qobs,
                                                  const float* __restrict__ kv,
                                                  float* __restrict__ wobs) {
  const int h = blockIdx.x >> 7;
  const int i = blockIdx.x & 127;
  const int t = threadIdx.x;
  const int jmax = S_ - OBS_ + i;
  __shared__ float qrow[G_][D_];
  __shared__ float srow[G_][S_];
  __shared__ float red[256];
  if (t < D_) {
#pragma unroll
    for (int g = 0; g < G_; ++g)
      qrow[g][t] = qobs[(size_t)i * NQ_ + (h * G_ + g) * D_ + t];
  }
  __syncthreads();
  float sm0 = -INFINITY, sm1 = -INFINITY, sm2 = -INFINITY, sm3 = -INFINITY;
  for (int j = t; j <= jmax; j += 256) {
    const float4* kp = (const float4*)(kv + (size_t)j * KLD_ + h * D_);
    float a0 = 0.f, a1 = 0.f, a2 = 0.f, a3 = 0.f;
#pragma unroll
    for (int d4 = 0; d4 < 32; ++d4) {
      float4 kvv = kp[d4];
      a0 += qrow[0][d4 * 4 + 0] * kvv.x + qrow[0][d4 * 4 + 1] * kvv.y +
            qrow[0][d4 * 4 + 2] * kvv.z + qrow[0][d4 * 4 + 3] * kvv.w;
      a1 += qrow[1][d4 * 4 + 0] * kvv.x + qrow[1][d4 * 4 + 1] * kvv.y +
            qrow[1][d4 * 4 + 2] * kvv.z + qrow[1][d4 * 4 + 3] * kvv.w;
      a2 += qrow[2][d4 * 4 + 0] * kvv.x + qrow[2][d4 * 4 + 1] * kvv.y +
            qrow[2][d4 * 4 + 2] * kvv.z + qrow[2][d4 * 4 + 3] * kvv.w;
      a3 += qrow[3][d4 * 4 + 0] * kvv.x + qrow[3][d4 * 4 + 1] * kvv.y +
            qrow[3][d4 * 4 + 2] * kvv.z + qrow[3][d4 * 4 + 3] * kvv.w;
    }
    a0 *= SCALE_; a1 *= SCALE_; a2 *= SCALE_; a3 *= SCALE_;
    srow[0][j] = a0; srow[1][j] = a1; srow[2][j] = a2; srow[3][j] = a3;
    sm0 = fmaxf(sm0, a0); sm1 = fmaxf(sm1, a1); sm2 = fmaxf(sm2, a2); sm3 = fmaxf(sm3, a3);
  }
  float smg[4] = {sm0, sm1, sm2, sm3};
  float rd[4];
#pragma unroll
  for (int g = 0; g < 4; ++g) {
    red[t] = smg[g]; __syncthreads();
    for (int off = 128; off > 0; off >>= 1) {
      if (t < off) red[t] = fmaxf(red[t], red[t + off]);
      __syncthreads();
    }
    float mx = red[0]; __syncthreads();
    float ssum = 0.f;
    for (int j = t; j <= jmax; j += 256) {
      float p = expf(srow[g][j] - mx);
      srow[g][j] = p;
      ssum += p;
    }
    red[t] = ssum; __syncthreads();
    for (int off = 128; off > 0; off >>= 1) {
      if (t < off) red[t] += red[t + off];
      __syncthreads();
    }
    rd[g] = 1.0f / red[0]; __syncthreads();
  }
  for (int j = t; j < S_; j += 256) {
    float v = 0.f;
    if (j <= jmax)
      v = (srow[0][j] * rd[0] + srow[1][j] * rd[1] + srow[2][j] * rd[2] + srow[3][j] * rd[3]) * 0.25f;
    wobs[(size_t)(h * OBS_ + i) * S_ + j] = v;
  }
}

// ---------------- imp ----------------
__global__ void imp_kernel(const float* __restrict__ wobs, float* __restrict__ imp) {
  int idx = blockIdx.x * 256 + threadIdx.x;
  if (idx >= HKV_ * S_) return;
  int h = idx >> 11;
  int j = idx & 2047;
  float s = 0.f;
  for (int i = 0; i < OBS_; ++i) s += wobs[(size_t)(h * OBS_ + i) * S_ + j];
  float cnt = (float)min(OBS_, S_ - j);
  imp[idx] = s / cnt;
}

// ---------------- radix select for quantile order statistics ----------------
__global__ void radix_init(unsigned* prefix, unsigned* kneed) {
  if (threadIdx.x == 0) {
    prefix[0] = prefix[1] = prefix[2] = prefix[3] = 0u;
    kneed[0] = 3225u; kneed[1] = 3226u; kneed[2] = 15320u; kneed[3] = 15321u;
  }
}
__global__ __launch_bounds__(256) void radix_hist(const float* __restrict__ imp,
                                                  const unsigned* __restrict__ prefix,
                                                  int pass, unsigned* __restrict__ hist) {
  __shared__ unsigned lh[1024];
  int t = threadIdx.x;
  for (int i = t; i < 1024; i += 256) lh[i] = 0u;
  __syncthreads();
  int idx = blockIdx.x * 256 + t;
  if (idx < NC_) {
    int h = idx / (S_ - W_), j = idx - h * (S_ - W_);
    union { float f; unsigned u; } cv; cv.f = imp[h * S_ + j];
    unsigned u = cv.u;
    int shift = 24 - pass * 8;
#pragma unroll
    for (int t4 = 0; t4 < 4; ++t4) {
      bool m = (pass == 0) || ((u >> (shift + 8)) == (prefix[t4] >> (shift + 8)));
      if (m) atomicAdd(&lh[t4 * 256 + ((u >> shift) & 255u)], 1u);
    }
  }
  __syncthreads();
  for (int i = t; i < 1024; i += 256) if (lh[i]) atomicAdd(&hist[i], lh[i]);
}
__global__ void radix_scan(const unsigned* __restrict__ hist, unsigned* prefix,
                           unsigned* kneed, int pass, float* thr) {
  int t = threadIdx.x;
  __shared__ unsigned selbits[4];
  if (t < 4) {
    unsigned need = kneed[t];
    unsigned cum = 0;
    int shift = 24 - pass * 8;
    unsigned pfx = prefix[t];
    for (int d = 0; d < 256; ++d) {
      unsigned c = hist[t * 256 + d];
      if (cum + c > need) { pfx |= ((unsigned)d) << shift; kneed[t] = need - cum; break; }
      cum += c;
    }
    prefix[t] = pfx;
    selbits[t] = pfx;
  }
  __syncthreads();
  if (pass == 3 && t == 0) {
    union { unsigned u; float f; } c0, c1, c2, c3;
    c0.u = selbits[0]; c1.u = selbits[1]; c2.u = selbits[2]; c3.u = selbits[3];
    double fl = 0.2 * (double)(NC_ - 1) - 3225.0;
    double fh = 0.95 * (double)(NC_ - 1) - 15320.0;
    thr[0] = (float)((double)c2.f + ((double)c3.f - (double)c2.f) * fh);
    thr[1] = (float)((double)c0.f + ((double)c1.f - (double)c0.f) * fl);
  }
}

// ---------------- levels + top-k sparsify ----------------
__global__ __launch_bounds__(128) void sparsify_kernel(const float* __restrict__ kv,
                                                       const float* __restrict__ imp,
                                                       const float* __restrict__ thr,
                                                       ushort_t* __restrict__ ksp,
                                                       ushort_t* __restrict__ vsp,
                                                       float* __restrict__ ebias) {
  const int b = blockIdx.x;
  const int j = b >> 3;
  const int h = b & 7;
  const int t = threadIdx.x;
  float ipv = imp[h * S_ + j];
  bool dense = (j >= S_ - W_) || (j < 2);
  int lvl = dense ? 0 : ((ipv >= thr[0]) ? 0 : ((ipv < thr[1]) ? 2 : 1));
  if (t == 0) ebias[h * S_ + j] = (lvl == 2) ? -INFINITY : 0.0f;
  __shared__ float av[128];
  __shared__ float thv;
  size_t base_in = (size_t)j * KLD_ + h * D_;
  size_t base_out = (size_t)j * NKV_ + h * D_;
  float kvv = kv[base_in + t];
  av[t] = fabsf(kvv);
  __syncthreads();
  {
    float at = av[t]; int cnt = 0;
    for (int m = 0; m < 128; ++m) { float am = av[m]; cnt += (am < at) || (am == at && m < t); }
    if (cnt == THR_IDX_) thv = at;
  }
  __syncthreads();
  {
    bool keep = (lvl == 0) || (lvl == 1 && fabsf(kvv) >= thv);
    ksp[base_out + t] = f2bf(keep ? kvv : 0.0f);
  }
  __syncthreads();
  float vvv = kv[base_in + 1024 + t];
  av[t] = fabsf(vvv);
  __syncthreads();
  {
    float at = av[t]; int cnt = 0;
    for (int m = 0; m < 128; ++m) { float am = av[m]; cnt += (am < at) || (am == at && m < t); }
    if (cnt == THR_IDX_) thv = at;
  }
  __syncthreads();
  {
    bool keep = (lvl == 0) || (lvl == 1 && fabsf(vvv) >= thv);
    vsp[base_out + t] = f2bf(keep ? vvv : 0.0f);
  }
}

// ---------------- main causal sparse attention (bf16 MFMA, flash-style) ----------------
__global__ __launch_bounds__(256) void attn_kernel(const ushort_t* __restrict__ qbp,
                                                   const ushort_t* __restrict__ ksp,
                                                   const ushort_t* __restrict__ vsp,
                                                   const float* __restrict__ ebias,
                                                   ushort_t* __restrict__ ob16) {
  __shared__ ushort_t k_lds[32][136];
  __shared__ ushort_t v_ldsT[128][40];
  __shared__ ushort_t p_lds[4][16][40];
  const int h = blockIdx.y;
  const int hk = h >> 2;
  const int qb = blockIdx.x;
  const int t = threadIdx.x;
  const int wave = t >> 6;
  const int lane = t & 63;
  const int lc = lane & 15;
  const int lg = lane >> 4;
  const int q0 = qb * 64 + wave * 16;

  s16x8 qfrag[4];
#pragma unroll
  for (int db = 0; db < 4; ++db)
    qfrag[db] = *(const s16x8*)(qbp + (size_t)(q0 + lc) * NQ_ + h * D_ + db * 32 + lg * 8);

  f32x4 o[8];
#pragma unroll
  for (int n = 0; n < 8; ++n) o[n] = 0.f;
  float mrow[4] = {-INFINITY, -INFINITY, -INFINITY, -INFINITY};
  float lrow[4] = {0.f, 0.f, 0.f, 0.f};

  const int ntiles = 2 * qb + 2;
  for (int tile = 0; tile < ntiles; ++tile) {
    const int j0 = tile * 32;
    __syncthreads();
#pragma unroll
    for (int u = 0; u < 2; ++u) {
      int idx = t * 2 + u;
      int jj = idx >> 4;
      int du = (idx & 15) * 8;
      u16x8 kv8 = *(const u16x8*)(ksp + (size_t)(j0 + jj) * NKV_ + hk * D_ + du);
      *(u16x8*)&k_lds[jj][du] = kv8;
      u16x8 vv8 = *(const u16x8*)(vsp + (size_t)(j0 + jj) * NKV_ + hk * D_ + du);
#pragma unroll
      for (int e = 0; e < 8; ++e) v_ldsT[du + e][jj] = vv8[e];
    }
    __syncthreads();

    f32x4 sfr0 = 0.f, sfr1 = 0.f;
#pragma unroll
    for (int db = 0; db < 4; ++db) {
      s16x8 kf0 = *(const s16x8*)&k_lds[lc][db * 32 + lg * 8];
      s16x8 kf1 = *(const s16x8*)&k_lds[16 + lc][db * 32 + lg * 8];
      sfr0 = __builtin_amdgcn_mfma_f32_16x16x32_bf16(qfrag[db], kf0, sfr0, 0, 0, 0);
      sfr1 = __builtin_amdgcn_mfma_f32_16x16x32_bf16(qfrag[db], kf1, sfr1, 0, 0, 0);
    }
    float eb0 = ebias[hk * S_ + j0 + lc];
    float eb1 = ebias[hk * S_ + j0 + 16 + lc];
    float p0[4], p1[4], scl[4];
#pragma unroll
    for (int r = 0; r < 4; ++r) {
      int row = q0 + lg * 4 + r;
      float s0 = (j0 + lc <= row) ? sfr0[r] * SCALE_ + eb0 : -INFINITY;
      float s1 = (j0 + 16 + lc <= row) ? sfr1[r] * SCALE_ + eb1 : -INFINITY;
      float tm = fmaxf(s0, s1);
#pragma unroll
      for (int off = 1; off < 16; off <<= 1) tm = fmaxf(tm, __shfl_xor(tm, off, 64));
      float mnew = fmaxf(mrow[r], tm);
      float sc_ = expf(mrow[r] - mnew);
      float e0 = expf(s0 - mnew);
      float e1 = expf(s1 - mnew);
      float ps = e0 + e1;
#pragma unroll
      for (int off = 1; off < 16; off <<= 1) ps += __shfl_xor(ps, off, 64);
      lrow[r] = lrow[r] * sc_ + ps;
      mrow[r] = mnew;
      scl[r] = sc_;
      p0[r] = e0; p1[r] = e1;
    }
#pragma unroll
    for (int n = 0; n < 8; ++n) {
      f32x4 ov = o[n];
#pragma unroll
      for (int r = 0; r < 4; ++r) ov[r] *= scl[r];
      o[n] = ov;
    }
#pragma unroll
    for (int r = 0; r < 4; ++r) {
      p_lds[wave][lg * 4 + r][lc] = f2bf(p0[r]);
      p_lds[wave][lg * 4 + r][16 + lc] = f2bf(p1[r]);
    }
    asm volatile("s_waitcnt lgkmcnt(0)" ::: "memory");
    s16x8 pa = *(const s16x8*)&p_lds[wave][lc][lg * 8];
#pragma unroll
    for (int n = 0; n < 8; ++n) {
      s16x8 vfrag = *(const s16x8*)&v_ldsT[n * 16 + lc][lg * 8];
      o[n] = __builtin_amdgcn_mfma_f32_16x16x32_bf16(pa, vfrag, o[n], 0, 0, 0);
    }
  }
#pragma unroll
  for (int r = 0; r < 4; ++r) {
    float rinv = 1.0f / lrow[r];
    int row = q0 + lg * 4 + r;
#pragma unroll
    for (int n = 0; n < 8; ++n)
      ob16[(size_t)row * NQ_ + h * D_ + n * 16 + lc] = f2bf(o[n][r] * rinv);
  }
}

// ---------------- launcher ----------------
extern "C" void kernel_launch(void* const* d_in, const int* in_sizes, int n_in,
                              void* d_out, int out_size, void* d_ws, size_t ws_size,
                              hipStream_t stream) {
  (void)in_sizes; (void)n_in; (void)out_size; (void)ws_size;
  const float* hid = (const float*)d_in[0];
  const float* wq  = (const float*)d_in[1];
  const float* wk  = (const float*)d_in[2];
  const float* wv  = (const float*)d_in[3];
  const float* wo  = (const float*)d_in[4];
  float* out = (float*)d_out;
  char* ws = (char*)d_ws;
  const size_t MB = 1ull << 20;

  ushort_t* h0     = (ushort_t*)(ws + 0 * MB);
  ushort_t* h1     = (ushort_t*)(ws + 16 * MB);
  ushort_t* h2     = (ushort_t*)(ws + 32 * MB);
  ushort_t* wq0T   = (ushort_t*)(ws + 48 * MB);   // later reused as qpart
  float*    qpart  = (float*)(ws + 48 * MB);
  ushort_t* wkv0T  = (ushort_t*)(ws + 80 * MB);
  ushort_t* wkv1T  = (ushort_t*)(ws + 96 * MB);
  ushort_t* wkv2T  = (ushort_t*)(ws + 112 * MB);
  float*    qf     = (float*)(ws + 128 * MB);
  float*    kvf    = (float*)(ws + 160 * MB);
  ushort_t* qb16   = (ushort_t*)(ws + 176 * MB);
  float*    qobs   = (float*)(ws + 192 * MB);
  ushort_t* ksp    = (ushort_t*)(ws + 195 * MB);
  ushort_t* vsp    = (ushort_t*)(ws + 199 * MB);
  ushort_t* ob16   = (ushort_t*)(ws + 203 * MB);
  float*    wobs   = (float*)(ws + 219 * MB);
  float*    impv   = (float*)(ws + 227 * MB);
  float*    eb     = (float*)(ws + 228 * MB);
  float*    invf   = (float*)(ws + 229 * MB);
  float*    thr    = (float*)(ws + 229 * MB + 4096);
  unsigned* prefix = (unsigned*)(ws + 229 * MB + 8192);
  unsigned* kneed  = (unsigned*)(ws + 229 * MB + 12288);
  unsigned* hist   = (unsigned*)(ws + 229 * MB + 16384);
  ushort_t* woT    = (ushort_t*)(ws + 0 * MB);    // overlays h0+h1 after they are dead

  // 1) splits
  split3_kernel<<<(S_ * HID_ / 4 + 255) / 256, 256, 0, stream>>>(hid, h0, h1, h2, S_ * HID_ / 4);
  splitT_kernel<<<dim3(NQ_ / 64, HID_ / 64), 256, 0, stream>>>(wq, NQ_, wq0T, nullptr, nullptr);
  splitT_kernel<<<dim3(NKV_ / 64, HID_ / 64), 256, 0, stream>>>(wk, NKV_, wkv0T, wkv1T, wkv2T);
  splitT_kernel<<<dim3(NKV_ / 64, HID_ / 64), 256, 0, stream>>>(
      wv, NKV_, wkv0T + (size_t)NKV_ * HID_, wkv1T + (size_t)NKV_ * HID_, wkv2T + (size_t)NKV_ * HID_);

  // 2) K|V combined GEMM, 6-product bf16 (fp32-grade)
  gemm_bt<1><<<dim3(2048 / 128, S_ / 128), 256, 0, stream>>>(h0, h1, wkv0T, wkv1T, kvf, S_, 2048, HID_);
  gemm_bt<2><<<dim3(2048 / 128, S_ / 128), 256, 0, stream>>>(h0, h2, wkv0T, wkv2T, kvf, S_, 2048, HID_);

  // 3) Q main GEMM, 1-product bf16
  gemm_bt<0><<<dim3(NQ_ / 128, S_ / 128), 256, 0, stream>>>(h0, nullptr, wq0T, nullptr, qf, S_, NQ_, HID_);

  // 4) obs-Q exact fp32 (128 rows), K-split then reduce  (reuses wq0T region as qpart)
  gemm_obsq<<<dim3(NQ_ / 128, 1, 16), 256, 0, stream>>>(hid + (size_t)(S_ - OBS_) * HID_, wq, qpart);
  reduce16_kernel<<<(OBS_ * NQ_ + 255) / 256, 256, 0, stream>>>(qpart, qobs, OBS_ * NQ_);

  // 5) wo transpose+cast into dead h0/h1 region
  splitT_kernel<<<dim3(HID_ / 64, HID_ / 64), 256, 0, stream>>>(wo, HID_, woT, nullptr, nullptr);

  // 6) RoPE
  freq_kernel<<<1, 64, 0, stream>>>(invf);
  rope_kernel<<<(S_ * HQ_ * 64 + 255) / 256, 256, 0, stream>>>(qf, qb16, invf, HQ_, NQ_, 0, S_ * HQ_ * 64);
  rope_kernel<<<(S_ * HKV_ * 64 + 255) / 256, 256, 0, stream>>>(kvf, nullptr, invf, HKV_, KLD_, 0, S_ * HKV_ * 64);
  rope_kernel<<<(OBS_ * HQ_ * 64 + 255) / 256, 256, 0, stream>>>(qobs, nullptr, invf, HQ_, NQ_, S_ - OBS_, OBS_ * HQ_ * 64);

  // 7) importance pipeline
  obs_kernel<<<HKV_ * OBS_, 256, 0, stream>>>(qobs, kvf, wobs);
  imp_kernel<<<(HKV_ * S_ + 255) / 256, 256, 0, stream>>>(wobs, impv);
  radix_init<<<1, 64, 0, stream>>>(prefix, kneed);
  for (int pass = 0; pass < 4; ++pass) {
    hipMemsetAsync(hist, 0, 4096, stream);
    radix_hist<<<(NC_ + 255) / 256, 256, 0, stream>>>(impv, prefix, pass, hist);
    radix_scan<<<1, 64, 0, stream>>>(hist, prefix, kneed, pass, thr);
  }

  // 8) sparsify + attention + out projection
  sparsify_kernel<<<S_ * HKV_, 128, 0, stream>>>(kvf, impv, thr, ksp, vsp, eb);
  attn_kernel<<<dim3(S_ / 64, HQ_), 256, 0, stream>>>(qb16, ksp, vsp, eb, ob16);
  gemm_bt<0><<<dim3(HID_ / 128, S_ / 128), 256, 0, stream>>>(ob16, nullptr, woT, nullptr, out, S_, HID_, HID_);
}

// Round 3
// 1068.480 us; speedup vs baseline: 2.8063x; 1.2270x over previous
//
#include <hip/hip_runtime.h>
#include <hip/hip_bf16.h>
#include <math.h>

#define S_    2048
#define HID_  4096
#define HQ_   32
#define HKV_  8
#define D_    128
#define G_    4
#define OBS_  128
#define W_    32
#define NKV_  1024
#define NQ_   4096
#define KLD_  2048
#define SCALE_ 0.08838834764831845f
#define THR_IDX_ 89
#define NC_   16128

typedef __attribute__((ext_vector_type(4))) float f32x4;
typedef __attribute__((ext_vector_type(8))) short s16x8;
typedef __attribute__((ext_vector_type(8))) unsigned short u16x8;
typedef __attribute__((ext_vector_type(4))) unsigned short u16x4;
typedef unsigned short ushort_t;

__device__ __forceinline__ unsigned short f2bf(float x) {
  union { float f; unsigned u; } v; v.f = x;
  unsigned r = v.u + 0x7FFFu + ((v.u >> 16) & 1u);
  return (unsigned short)(r >> 16);
}
__device__ __forceinline__ float bf2f(unsigned short b) {
  union { unsigned u; float f; } v; v.u = ((unsigned)b) << 16;
  return v.f;
}
__device__ __forceinline__ void gload_lds16(const void* g, void* l) {
  __builtin_amdgcn_global_load_lds((const __attribute__((address_space(1))) unsigned int*)g,
                                   (__attribute__((address_space(3))) unsigned int*)l, 16, 0, 0);
}

// ---------------- split fp32 -> 3 bf16 terms ----------------
__global__ __launch_bounds__(256) void split3_kernel(const float* __restrict__ src,
                                                     ushort_t* __restrict__ d0,
                                                     ushort_t* __restrict__ d1,
                                                     ushort_t* __restrict__ d2, int n4) {
  int idx = blockIdx.x * 256 + threadIdx.x;
  if (idx >= n4) return;
  float4 v = ((const float4*)src)[idx];
  u16x4 o0, o1, o2;
  float xs[4] = {v.x, v.y, v.z, v.w};
#pragma unroll
  for (int e = 0; e < 4; ++e) {
    float x = xs[e];
    unsigned short b0 = f2bf(x);
    float r = x - bf2f(b0);
    unsigned short b1 = f2bf(r);
    float r2 = r - bf2f(b1);
    unsigned short b2 = f2bf(r2);
    o0[e] = b0; o1[e] = b1; o2[e] = b2;
  }
  *(u16x4*)(d0 + (size_t)idx * 4) = o0;
  *(u16x4*)(d1 + (size_t)idx * 4) = o1;
  *(u16x4*)(d2 + (size_t)idx * 4) = o2;
}

// ---------------- split + transpose weights ----------------
__global__ __launch_bounds__(256) void splitT_kernel(const float* __restrict__ src, int N,
                                                     ushort_t* __restrict__ t0,
                                                     ushort_t* __restrict__ t1,
                                                     ushort_t* __restrict__ t2) {
  __shared__ float tile[64][65];
  const int t = threadIdx.x;
  const int n0 = blockIdx.x * 64, k0 = blockIdx.y * 64;
#pragma unroll
  for (int i = 0; i < 16; ++i) {
    int idx = i * 256 + t;
    int r = idx >> 6, c = idx & 63;
    tile[r][c] = src[(size_t)(k0 + r) * N + n0 + c];
  }
  __syncthreads();
#pragma unroll
  for (int i = 0; i < 16; ++i) {
    int idx = i * 256 + t;
    int n = idx >> 6, kk = idx & 63;
    float x = tile[kk][n];
    unsigned short b0 = f2bf(x);
    size_t o = (size_t)(n0 + n) * HID_ + k0 + kk;
    t0[o] = b0;
    if (t1) {
      float r = x - bf2f(b0);
      unsigned short b1 = f2bf(r);
      t1[o] = b1;
      float r2 = r - bf2f(b1);
      t2[o] = f2bf(r2);
    }
  }
}

// ---------------- unified bf16 MFMA GEMM ----------------
template<int MODE>
__global__ __launch_bounds__(256) void gemm_bt(const ushort_t* __restrict__ A0,
                                               const ushort_t* __restrict__ A1,
                                               const ushort_t* __restrict__ B0,
                                               const ushort_t* __restrict__ B1,
                                               float* __restrict__ C,
                                               int M, int N, int K) {
  constexpr int NT = (MODE == 0) ? 2 : 4;
  __shared__ ushort_t lds[NT * 128 * 64];
  const int t = threadIdx.x;
  const int wave = t >> 6, lane = t & 63;
  const int lc = lane & 15, lg = lane >> 4;
  const int bm = blockIdx.y, bn = blockIdx.x;
  const int wm = wave >> 1, wn = wave & 1;
  const int srow = t >> 3;
  const int schunk = t & 7;

  f32x4 acc[4][4];
#pragma unroll
  for (int fi = 0; fi < 4; ++fi)
#pragma unroll
    for (int fj = 0; fj < 4; ++fj) acc[fi][fj] = 0.f;

  for (int kb = 0; kb < K / 64; ++kb) {
    __syncthreads();
#pragma unroll
    for (int tid = 0; tid < NT; ++tid) {
      const ushort_t* src = (tid == 0) ? A0 : (tid == 1) ? B0 : (tid == 2) ? A1 : B1;
      const int rb = (tid == 0 || tid == 2) ? bm : bn;
#pragma unroll
      for (int g = 0; g < 4; ++g) {
        int row = g * 32 + srow;
        int sw = schunk ^ (row & 7);
        const ushort_t* gp = src + (size_t)(rb * 128 + row) * K + kb * 64 + sw * 8;
        ushort_t* lp = lds + tid * 8192 + g * 2048 + wave * 512;
        gload_lds16(gp, lp);
      }
    }
    __syncthreads();
#pragma unroll
    for (int ks = 0; ks < 2; ++ks) {
      s16x8 a0f[4], b0f[4], a1f[4], b1f[4];
#pragma unroll
      for (int f = 0; f < 4; ++f) {
        int ra = wm * 64 + f * 16 + lc;
        int ca = ((ks * 4 + lg) ^ (ra & 7)) * 8;
        a0f[f] = *(const s16x8*)(lds + 0 * 8192 + ra * 64 + ca);
        int rb2 = wn * 64 + f * 16 + lc;
        int cb = ((ks * 4 + lg) ^ (rb2 & 7)) * 8;
        b0f[f] = *(const s16x8*)(lds + 1 * 8192 + rb2 * 64 + cb);
        if constexpr (MODE >= 1) {
          a1f[f] = *(const s16x8*)(lds + 2 * 8192 + ra * 64 + ca);
          b1f[f] = *(const s16x8*)(lds + 3 * 8192 + rb2 * 64 + cb);
        }
      }
#pragma unroll
      for (int fi = 0; fi < 4; ++fi)
#pragma unroll
        for (int fj = 0; fj < 4; ++fj) {
          if constexpr (MODE == 0) {
            acc[fi][fj] = __builtin_amdgcn_mfma_f32_16x16x32_bf16(a0f[fi], b0f[fj], acc[fi][fj], 0, 0, 0);
          } else if constexpr (MODE == 1) {
            acc[fi][fj] = __builtin_amdgcn_mfma_f32_16x16x32_bf16(a0f[fi], b0f[fj], acc[fi][fj], 0, 0, 0);
            acc[fi][fj] = __builtin_amdgcn_mfma_f32_16x16x32_bf16(a0f[fi], b1f[fj], acc[fi][fj], 0, 0, 0);
            acc[fi][fj] = __builtin_amdgcn_mfma_f32_16x16x32_bf16(a1f[fi], b0f[fj], acc[fi][fj], 0, 0, 0);
            acc[fi][fj] = __builtin_amdgcn_mfma_f32_16x16x32_bf16(a1f[fi], b1f[fj], acc[fi][fj], 0, 0, 0);
          } else {
            acc[fi][fj] = __builtin_amdgcn_mfma_f32_16x16x32_bf16(a0f[fi], b1f[fj], acc[fi][fj], 0, 0, 0);
            acc[fi][fj] = __builtin_amdgcn_mfma_f32_16x16x32_bf16(a1f[fi], b0f[fj], acc[fi][fj], 0, 0, 0);
          }
        }
    }
  }
#pragma unroll
  for (int fi = 0; fi < 4; ++fi)
#pragma unroll
    for (int fj = 0; fj < 4; ++fj)
#pragma unroll
      for (int r = 0; r < 4; ++r) {
        size_t o = (size_t)(bm * 128 + wm * 64 + fi * 16 + lg * 4 + r) * N +
                   bn * 128 + wn * 64 + fj * 16 + lc;
        if constexpr (MODE == 2) C[o] += acc[fi][fj][r];
        else C[o] = acc[fi][fj][r];
      }
}

// ---------------- fp32 obs-Q GEMM (exact fp32 decision path) ----------------
__global__ __launch_bounds__(256) void gemm_obsq(const float* __restrict__ A,
                                                 const float* __restrict__ Bw,
                                                 float* __restrict__ Cp) {
  __shared__ float a_t[16][136];
  __shared__ float b_t[16][136];
  const int t = threadIdx.x, tx = t & 15, ty = t >> 4;
  const int bn = blockIdx.x, z = blockIdx.z;
  float acc[8][8];
#pragma unroll
  for (int i = 0; i < 8; i++)
#pragma unroll
    for (int j = 0; j < 8; j++) acc[i][j] = 0.f;
  for (int kb = z * 16; kb < z * 16 + 16; ++kb) {
    __syncthreads();
#pragma unroll
    for (int u = 0; u < 2; ++u) {
      int idx = t * 2 + u;
      int r = idx >> 2, c4 = idx & 3;
      float4 va = *(const float4*)(A + (size_t)r * HID_ + kb * 16 + c4 * 4);
      a_t[c4 * 4 + 0][r] = va.x; a_t[c4 * 4 + 1][r] = va.y;
      a_t[c4 * 4 + 2][r] = va.z; a_t[c4 * 4 + 3][r] = va.w;
      int rb = idx >> 5, cb = idx & 31;
      float4 vb = *(const float4*)(Bw + (size_t)(kb * 16 + rb) * NQ_ + bn * 128 + cb * 4);
      *(float4*)&b_t[rb][cb * 4] = vb;
    }
    __syncthreads();
#pragma unroll
    for (int kk = 0; kk < 16; ++kk) {
      float a0[8], b0[8];
      *(float4*)&a0[0] = *(const float4*)&a_t[kk][ty * 8];
      *(float4*)&a0[4] = *(const float4*)&a_t[kk][ty * 8 + 4];
      *(float4*)&b0[0] = *(const float4*)&b_t[kk][tx * 8];
      *(float4*)&b0[4] = *(const float4*)&b_t[kk][tx * 8 + 4];
#pragma unroll
      for (int i = 0; i < 8; i++)
#pragma unroll
        for (int j = 0; j < 8; j++) acc[i][j] = fmaf(a0[i], b0[j], acc[i][j]);
    }
  }
  float* cp0 = Cp + (size_t)z * 128 * NQ_;
#pragma unroll
  for (int i = 0; i < 8; i++) {
    float* cp = cp0 + (size_t)(ty * 8 + i) * NQ_ + bn * 128 + tx * 8;
    *(float4*)cp = *(float4*)&acc[i][0];
    *(float4*)(cp + 4) = *(float4*)&acc[i][4];
  }
}

__global__ void reduce16_kernel(const float* __restrict__ Cp, float* __restrict__ out, int n) {
  int idx = blockIdx.x * 256 + threadIdx.x;
  if (idx >= n) return;
  float s = 0.f;
#pragma unroll
  for (int z = 0; z < 16; ++z) s += Cp[(size_t)z * n + idx];
  out[idx] = s;
}

// ---------------- inv_freq ----------------
__global__ void freq_kernel(float* __restrict__ invf) {
  int j = threadIdx.x;
  if (j < 64) invf[j] = (float)(1.0 / pow(500000.0, (double)j / 64.0));
}

// ---------------- RoPE ----------------
__global__ void rope_kernel(float* __restrict__ X, ushort_t* __restrict__ Xb,
                            const float* __restrict__ invf, int H, int ld, int pos0, int total) {
  int idx = blockIdx.x * 256 + threadIdx.x;
  if (idx >= total) return;
  int j = idx & 63;
  int h = (idx >> 6) % H;
  int s = idx / (64 * H);
  float ang = (float)(pos0 + s) * invf[j];
  float sn, cs;
  sincosf(ang, &sn, &cs);
  size_t base = (size_t)s * ld + h * D_ + j;
  float x1 = X[base], x2 = X[base + 64];
  float o1 = x1 * cs - x2 * sn;
  float o2 = x2 * cs + x1 * sn;
  X[base] = o1; X[base + 64] = o2;
  if (Xb) { Xb[base] = f2bf(o1); Xb[base + 64] = f2bf(o2); }
}

// ---------------- observation attention ----------------
__global__ __launch_bounds__(256) void obs_kernel(const float* __restrict__ qobs,
                                                  const float* __restrict__ kv,
                                                  float* __restrict__ wobs) {
  const int h = blockIdx.x >> 7;
  const int i = blockIdx.x & 127;
  const int t = threadIdx.x;
  const int jmax = S_ - OBS_ + i;
  __shared__ float qrow[G_][D_];
  __shared__ float srow[G_][S_];
  __shared__ float red[256];
  if (t < D_) {
#pragma unroll
    for (int g = 0; g < G_; ++g)
      qrow[g][t] = qobs[(size_t)i * NQ_ + (h * G_ + g) * D_ + t];
  }
  __syncthreads();
  float sm0 = -INFINITY, sm1 = -INFINITY, sm2 = -INFINITY, sm3 = -INFINITY;
  for (int j = t; j <= jmax; j += 256) {
    const float4* kp = (const float4*)(kv + (size_t)j * KLD_ + h * D_);
    float a0 = 0.f, a1 = 0.f, a2 = 0.f, a3 = 0.f;
#pragma unroll
    for (int d4 = 0; d4 < 32; ++d4) {
      float4 kvv = kp[d4];
      a0 += qrow[0][d4 * 4 + 0] * kvv.x + qrow[0][d4 * 4 + 1] * kvv.y +
            qrow[0][d4 * 4 + 2] * kvv.z + qrow[0][d4 * 4 + 3] * kvv.w;
      a1 += qrow[1][d4 * 4 + 0] * kvv.x + qrow[1][d4 * 4 + 1] * kvv.y +
            qrow[1][d4 * 4 + 2] * kvv.z + qrow[1][d4 * 4 + 3] * kvv.w;
      a2 += qrow[2][d4 * 4 + 0] * kvv.x + qrow[2][d4 * 4 + 1] * kvv.y +
            qrow[2][d4 * 4 + 2] * kvv.z + qrow[2][d4 * 4 + 3] * kvv.w;
      a3 += qrow[3][d4 * 4 + 0] * kvv.x + qrow[3][d4 * 4 + 1] * kvv.y +
            qrow[3][d4 * 4 + 2] * kvv.z + qrow[3][d4 * 4 + 3] * kvv.w;
    }
    a0 *= SCALE_; a1 *= SCALE_; a2 *= SCALE_; a3 *= SCALE_;
    srow[0][j] = a0; srow[1][j] = a1; srow[2][j] = a2; srow[3][j] = a3;
    sm0 = fmaxf(sm0, a0); sm1 = fmaxf(sm1, a1); sm2 = fmaxf(sm2, a2); sm3 = fmaxf(sm3, a3);
  }
  float smg[4] = {sm0, sm1, sm2, sm3};
  float rd[4];
#pragma unroll
  for (int g = 0; g < 4; ++g) {
    red[t] = smg[g]; __syncthreads();
    for (int off = 128; off > 0; off >>= 1) {
      if (t < off) red[t] = fmaxf(red[t], red[t + off]);
      __syncthreads();
    }
    float mx = red[0]; __syncthreads();
    float ssum = 0.f;
    for (int j = t; j <= jmax; j += 256) {
      float p = expf(srow[g][j] - mx);
      srow[g][j] = p;
      ssum += p;
    }
    red[t] = ssum; __syncthreads();
    for (int off = 128; off > 0; off >>= 1) {
      if (t < off) red[t] += red[t + off];
      __syncthreads();
    }
    rd[g] = 1.0f / red[0]; __syncthreads();
  }
  for (int j = t; j < S_; j += 256) {
    float v = 0.f;
    if (j <= jmax)
      v = (srow[0][j] * rd[0] + srow[1][j] * rd[1] + srow[2][j] * rd[2] + srow[3][j] * rd[3]) * 0.25f;
    wobs[(size_t)(h * OBS_ + i) * S_ + j] = v;
  }
}

// ---------------- imp ----------------
__global__ void imp_kernel(const float* __restrict__ wobs, float* __restrict__ imp) {
  int idx = blockIdx.x * 256 + threadIdx.x;
  if (idx >= HKV_ * S_) return;
  int h = idx >> 11;
  int j = idx & 2047;
  float s = 0.f;
  for (int i = 0; i < OBS_; ++i) s += wobs[(size_t)(h * OBS_ + i) * S_ + j];
  float cnt = (float)min(OBS_, S_ - j);
  imp[idx] = s / cnt;
}

// ---------------- radix select ----------------
__global__ void radix_init(unsigned* prefix, unsigned* kneed) {
  if (threadIdx.x == 0) {
    prefix[0] = prefix[1] = prefix[2] = prefix[3] = 0u;
    kneed[0] = 3225u; kneed[1] = 3226u; kneed[2] = 15320u; kneed[3] = 15321u;
  }
}
__global__ __launch_bounds__(256) void radix_hist(const float* __restrict__ imp,
                                                  const unsigned* __restrict__ prefix,
                                                  int pass, unsigned* __restrict__ hist) {
  __shared__ unsigned lh[1024];
  int t = threadIdx.x;
  for (int i = t; i < 1024; i += 256) lh[i] = 0u;
  __syncthreads();
  int idx = blockIdx.x * 256 + t;
  if (idx < NC_) {
    int h = idx / (S_ - W_), j = idx - h * (S_ - W_);
    union { float f; unsigned u; } cv; cv.f = imp[h * S_ + j];
    unsigned u = cv.u;
    int shift = 24 - pass * 8;
#pragma unroll
    for (int t4 = 0; t4 < 4; ++t4) {
      bool m = (pass == 0) || ((u >> (shift + 8)) == (prefix[t4] >> (shift + 8)));
      if (m) atomicAdd(&lh[t4 * 256 + ((u >> shift) & 255u)], 1u);
    }
  }
  __syncthreads();
  for (int i = t; i < 1024; i += 256) if (lh[i]) atomicAdd(&hist[i], lh[i]);
}
__global__ void radix_scan(const unsigned* __restrict__ hist, unsigned* prefix,
                           unsigned* kneed, int pass, float* thr) {
  int t = threadIdx.x;
  __shared__ unsigned selbits[4];
  if (t < 4) {
    unsigned need = kneed[t];
    unsigned cum = 0;
    int shift = 24 - pass * 8;
    unsigned pfx = prefix[t];
    for (int d = 0; d < 256; ++d) {
      unsigned c = hist[t * 256 + d];
      if (cum + c > need) { pfx |= ((unsigned)d) << shift; kneed[t] = need - cum; break; }
      cum += c;
    }
    prefix[t] = pfx;
    selbits[t] = pfx;
  }
  __syncthreads();
  if (pass == 3 && t == 0) {
    union { unsigned u; float f; } c0, c1, c2, c3;
    c0.u = selbits[0]; c1.u = selbits[1]; c2.u = selbits[2]; c3.u = selbits[3];
    double fl = 0.2 * (double)(NC_ - 1) - 3225.0;
    double fh = 0.95 * (double)(NC_ - 1) - 15320.0;
    thr[0] = (float)((double)c2.f + ((double)c3.f - (double)c2.f) * fh);
    thr[1] = (float)((double)c0.f + ((double)c1.f - (double)c0.f) * fl);
  }
}

// ---------------- sparsify ----------------
__global__ __launch_bounds__(128) void sparsify_kernel(const float* __restrict__ kv,
                                                       const float* __restrict__ imp,
                                                       const float* __restrict__ thr,
                                                       ushort_t* __restrict__ ksp,
                                                       ushort_t* __restrict__ vsp,
                                                       float* __restrict__ ebias) {
  const int b = blockIdx.x;
  const int j = b >> 3;
  const int h = b & 7;
  const int t = threadIdx.x;
  float ipv = imp[h * S_ + j];
  bool dense = (j >= S_ - W_) || (j < 2);
  int lvl = dense ? 0 : ((ipv >= thr[0]) ? 0 : ((ipv < thr[1]) ? 2 : 1));
  if (t == 0) ebias[h * S_ + j] = (lvl == 2) ? -INFINITY : 0.0f;
  __shared__ float av[128];
  __shared__ float thv;
  size_t base_in = (size_t)j * KLD_ + h * D_;
  size_t base_out = (size_t)j * NKV_ + h * D_;
  float kvv = kv[base_in + t];
  av[t] = fabsf(kvv);
  __syncthreads();
  {
    float at = av[t]; int cnt = 0;
    for (int m = 0; m < 128; ++m) { float am = av[m]; cnt += (am < at) || (am == at && m < t); }
    if (cnt == THR_IDX_) thv = at;
  }
  __syncthreads();
  {
    bool keep = (lvl == 0) || (lvl == 1 && fabsf(kvv) >= thv);
    ksp[base_out + t] = f2bf(keep ? kvv : 0.0f);
  }
  __syncthreads();
  float vvv = kv[base_in + 1024 + t];
  av[t] = fabsf(vvv);
  __syncthreads();
  {
    float at = av[t]; int cnt = 0;
    for (int m = 0; m < 128; ++m) { float am = av[m]; cnt += (am < at) || (am == at && m < t); }
    if (cnt == THR_IDX_) thv = at;
  }
  __syncthreads();
  {
    bool keep = (lvl == 0) || (lvl == 1 && fabsf(vvv) >= thv);
    vsp[base_out + t] = f2bf(keep ? vvv : 0.0f);
  }
}

// ---------------- V transpose: vsp[j][hk*128+d] -> vspT[hk][d][j] ----------------
__global__ __launch_bounds__(256) void vtrans_kernel(const ushort_t* __restrict__ vsp,
                                                     ushort_t* __restrict__ vspT) {
  __shared__ ushort_t tl[64][136];
  const int jt = blockIdx.x;   // 0..31
  const int hk = blockIdx.y;   // 0..7
  const int t = threadIdx.x;
#pragma unroll
  for (int i = 0; i < 4; ++i) {
    int idx = i * 256 + t;
    int j = idx >> 4, c = idx & 15;
    *(u16x8*)&tl[j][c * 8] = *(const u16x8*)(vsp + (size_t)(jt * 64 + j) * NKV_ + hk * 128 + c * 8);
  }
  __syncthreads();
  int d = t >> 1, j0 = (t & 1) * 32;
#pragma unroll
  for (int jj = 0; jj < 4; ++jj) {
    u16x8 v;
#pragma unroll
    for (int e = 0; e < 8; ++e) v[e] = tl[j0 + jj * 8 + e][d];
    *(u16x8*)(vspT + ((size_t)hk * 128 + d) * S_ + jt * 64 + j0 + jj * 8) = v;
  }
}

// ---------------- main attention: pair-balanced, KVBLK=64, gload_lds + swizzle ----------
#define SPAD_ 66
__global__ __launch_bounds__(256) void attn_kernel(const ushort_t* __restrict__ qbp,
                                                   const ushort_t* __restrict__ ksp,
                                                   const ushort_t* __restrict__ vspT,
                                                   const float* __restrict__ ebias,
                                                   ushort_t* __restrict__ ob16) {
  __shared__ ushort_t k_lds[64 * 128];    // [row j][16 chunks swizzled]
  __shared__ ushort_t vT_lds[128 * 64];   // [row d][8 chunks swizzled]
  __shared__ float s_lds[4][16][SPAD_];
  const int b = blockIdx.x;
  const int xcd = b & 7;
  const int idx = b >> 3;
  const int h = xcd * 4 + (idx >> 4);  // 4 q-heads (one kv-head) per XCD
  const int p = idx & 15;
  const int hk = h >> 2;
  const int t = threadIdx.x;
  const int w = t >> 6, lane = t & 63;
  const int lc = lane & 15, lg = lane >> 4;

  const ushort_t* kbase = ksp + hk * D_;
  const ushort_t* vbase = vspT + (size_t)hk * D_ * S_;

  for (int strip = 0; strip < 2; ++strip) {
    const int qb = (strip == 0) ? p : 31 - p;
    const int q0 = qb * 64 + w * 16;
    s16x8 qfrag[4];
#pragma unroll
    for (int db = 0; db < 4; ++db)
      qfrag[db] = *(const s16x8*)(qbp + (size_t)(q0 + lc) * NQ_ + h * D_ + db * 32 + lg * 8);

    f32x4 o[8];
#pragma unroll
    for (int n = 0; n < 8; ++n) o[n] = 0.f;
    float mr[4] = {-INFINITY, -INFINITY, -INFINITY, -INFINITY};
    float lr[4] = {0.f, 0.f, 0.f, 0.f};

    const int ntj = qb + 1;
    for (int tj = 0; tj < ntj; ++tj) {
      const int j0 = tj * 64;
      __syncthreads();
      // stage K tile [64][128] (16B chunks, chunk c holds global chunk c^(row&7))
#pragma unroll
      for (int i = 0; i < 4; ++i) {
        int slot = i * 256 + w * 64 + lane;
        int row = slot >> 4, c = slot & 15;
        const ushort_t* gp = kbase + (size_t)(j0 + row) * NKV_ + ((c ^ (row & 7)) * 8);
        gload_lds16(gp, &k_lds[(i * 256 + w * 64) * 8]);
      }
      // stage V^T tile [128][64]
#pragma unroll
      for (int i = 0; i < 4; ++i) {
        int slot = i * 256 + w * 64 + lane;
        int d = slot >> 3, c = slot & 7;
        const ushort_t* gp = vbase + (size_t)d * S_ + j0 + ((c ^ (d & 7)) * 8);
        gload_lds16(gp, &vT_lds[(i * 256 + w * 64) * 8]);
      }
      __syncthreads();

      // QK^T: 4 kv-subtiles x 4 db
      f32x4 sfr[4];
#pragma unroll
      for (int js = 0; js < 4; ++js) sfr[js] = 0.f;
#pragma unroll
      for (int js = 0; js < 4; ++js) {
        int row = js * 16 + lc;
#pragma unroll
        for (int db = 0; db < 4; ++db) {
          s16x8 kf = *(const s16x8*)&k_lds[row * 128 + (((db * 4 + lg) ^ (lc & 7)) * 8)];
          sfr[js] = __builtin_amdgcn_mfma_f32_16x16x32_bf16(qfrag[db], kf, sfr[js], 0, 0, 0);
        }
      }
      float eb[4];
#pragma unroll
      for (int js = 0; js < 4; ++js) eb[js] = ebias[hk * S_ + j0 + js * 16 + lc];

      const bool diag = (tj == qb);
      float sclv[4];
#pragma unroll
      for (int r = 0; r < 4; ++r) {
        float sv[4];
#pragma unroll
        for (int js = 0; js < 4; ++js) sv[js] = sfr[js][r] * SCALE_ + eb[js];
        if (diag) {
          int qrow = w * 16 + lg * 4 + r;
#pragma unroll
          for (int js = 0; js < 4; ++js)
            if (js * 16 + lc > qrow) sv[js] = -INFINITY;
        }
        float tm = fmaxf(fmaxf(sv[0], sv[1]), fmaxf(sv[2], sv[3]));
#pragma unroll
        for (int off = 1; off < 16; off <<= 1) tm = fmaxf(tm, __shfl_xor(tm, off, 64));
        float mnew = fmaxf(mr[r], tm);
        float scl = __expf(mr[r] - mnew);
        float ps = 0.f;
#pragma unroll
        for (int js = 0; js < 4; ++js) {
          float e = __expf(sv[js] - mnew);
          s_lds[w][lg * 4 + r][js * 16 + lc] = e;
          ps += e;
        }
#pragma unroll
        for (int off = 1; off < 16; off <<= 1) ps += __shfl_xor(ps, off, 64);
        lr[r] = lr[r] * scl + ps;
        mr[r] = mnew;
        sclv[r] = scl;
      }
#pragma unroll
      for (int n = 0; n < 8; ++n) {
        f32x4 ov = o[n];
#pragma unroll
        for (int r = 0; r < 4; ++r) ov[r] *= sclv[r];
        o[n] = ov;
      }
      asm volatile("s_waitcnt lgkmcnt(0)" ::: "memory");
      s16x8 pa[2];
#pragma unroll
      for (int ks = 0; ks < 2; ++ks) {
        float pv[8];
        *(f32x4*)&pv[0] = *(const f32x4*)&s_lds[w][lc][ks * 32 + lg * 8];
        *(f32x4*)&pv[4] = *(const f32x4*)&s_lds[w][lc][ks * 32 + lg * 8 + 4];
        s16x8 pk;
#pragma unroll
        for (int e = 0; e < 8; ++e) pk[e] = (short)f2bf(pv[e]);
        pa[ks] = pk;
      }
#pragma unroll
      for (int n = 0; n < 8; ++n) {
        int d = n * 16 + lc;
#pragma unroll
        for (int ks = 0; ks < 2; ++ks) {
          s16x8 vf = *(const s16x8*)&vT_lds[d * 64 + (((ks * 4 + lg) ^ (lc & 7)) * 8)];
          o[n] = __builtin_amdgcn_mfma_f32_16x16x32_bf16(pa[ks], vf, o[n], 0, 0, 0);
        }
      }
    }
    // epilogue for this strip
#pragma unroll
    for (int r = 0; r < 4; ++r) {
      float rinv = 1.0f / lr[r];
      int row = q0 + lg * 4 + r;
#pragma unroll
      for (int n = 0; n < 8; ++n)
        ob16[(size_t)row * NQ_ + h * D_ + n * 16 + lc] = f2bf(o[n][r] * rinv);
    }
  }
}

// ---------------- launcher ----------------
extern "C" void kernel_launch(void* const* d_in, const int* in_sizes, int n_in,
                              void* d_out, int out_size, void* d_ws, size_t ws_size,
                              hipStream_t stream) {
  (void)in_sizes; (void)n_in; (void)out_size; (void)ws_size;
  const float* hid = (const float*)d_in[0];
  const float* wq  = (const float*)d_in[1];
  const float* wk  = (const float*)d_in[2];
  const float* wv  = (const float*)d_in[3];
  const float* wo  = (const float*)d_in[4];
  float* out = (float*)d_out;
  char* ws = (char*)d_ws;
  const size_t MB = 1ull << 20;

  ushort_t* h0     = (ushort_t*)(ws + 0 * MB);
  ushort_t* h1     = (ushort_t*)(ws + 16 * MB);
  ushort_t* h2     = (ushort_t*)(ws + 32 * MB);
  ushort_t* wq0T   = (ushort_t*)(ws + 48 * MB);   // reused: qpart, then vspT
  float*    qpart  = (float*)(ws + 48 * MB);
  ushort_t* vspT   = (ushort_t*)(ws + 48 * MB);
  ushort_t* wkv0T  = (ushort_t*)(ws + 80 * MB);
  ushort_t* wkv1T  = (ushort_t*)(ws + 96 * MB);
  ushort_t* wkv2T  = (ushort_t*)(ws + 112 * MB);
  float*    qf     = (float*)(ws + 128 * MB);
  float*    kvf    = (float*)(ws + 160 * MB);
  ushort_t* qb16   = (ushort_t*)(ws + 176 * MB);
  float*    qobs   = (float*)(ws + 192 * MB);
  ushort_t* ksp    = (ushort_t*)(ws + 195 * MB);
  ushort_t* vsp    = (ushort_t*)(ws + 199 * MB);
  ushort_t* ob16   = (ushort_t*)(ws + 203 * MB);
  float*    wobs   = (float*)(ws + 219 * MB);
  float*    impv   = (float*)(ws + 227 * MB);
  float*    eb     = (float*)(ws + 228 * MB);
  float*    invf   = (float*)(ws + 229 * MB);
  float*    thr    = (float*)(ws + 229 * MB + 4096);
  unsigned* prefix = (unsigned*)(ws + 229 * MB + 8192);
  unsigned* kneed  = (unsigned*)(ws + 229 * MB + 12288);
  unsigned* hist   = (unsigned*)(ws + 229 * MB + 16384);
  ushort_t* woT    = (ushort_t*)(ws + 0 * MB);    // overlays h0+h1 after dead

  // 1) splits
  split3_kernel<<<(S_ * HID_ / 4 + 255) / 256, 256, 0, stream>>>(hid, h0, h1, h2, S_ * HID_ / 4);
  splitT_kernel<<<dim3(NQ_ / 64, HID_ / 64), 256, 0, stream>>>(wq, NQ_, wq0T, nullptr, nullptr);
  splitT_kernel<<<dim3(NKV_ / 64, HID_ / 64), 256, 0, stream>>>(wk, NKV_, wkv0T, wkv1T, wkv2T);
  splitT_kernel<<<dim3(NKV_ / 64, HID_ / 64), 256, 0, stream>>>(
      wv, NKV_, wkv0T + (size_t)NKV_ * HID_, wkv1T + (size_t)NKV_ * HID_, wkv2T + (size_t)NKV_ * HID_);

  // 2) K|V 6-product bf16 (fp32-grade)
  gemm_bt<1><<<dim3(2048 / 128, S_ / 128), 256, 0, stream>>>(h0, h1, wkv0T, wkv1T, kvf, S_, 2048, HID_);
  gemm_bt<2><<<dim3(2048 / 128, S_ / 128), 256, 0, stream>>>(h0, h2, wkv0T, wkv2T, kvf, S_, 2048, HID_);

  // 3) Q main GEMM (bf16 path)
  gemm_bt<0><<<dim3(NQ_ / 128, S_ / 128), 256, 0, stream>>>(h0, nullptr, wq0T, nullptr, qf, S_, NQ_, HID_);

  // 4) obs-Q exact fp32
  gemm_obsq<<<dim3(NQ_ / 128, 1, 16), 256, 0, stream>>>(hid + (size_t)(S_ - OBS_) * HID_, wq, qpart);
  reduce16_kernel<<<(OBS_ * NQ_ + 255) / 256, 256, 0, stream>>>(qpart, qobs, OBS_ * NQ_);

  // 5) wo transpose+cast
  splitT_kernel<<<dim3(HID_ / 64, HID_ / 64), 256, 0, stream>>>(wo, HID_, woT, nullptr, nullptr);

  // 6) RoPE
  freq_kernel<<<1, 64, 0, stream>>>(invf);
  rope_kernel<<<(S_ * HQ_ * 64 + 255) / 256, 256, 0, stream>>>(qf, qb16, invf, HQ_, NQ_, 0, S_ * HQ_ * 64);
  rope_kernel<<<(S_ * HKV_ * 64 + 255) / 256, 256, 0, stream>>>(kvf, nullptr, invf, HKV_, KLD_, 0, S_ * HKV_ * 64);
  rope_kernel<<<(OBS_ * HQ_ * 64 + 255) / 256, 256, 0, stream>>>(qobs, nullptr, invf, HQ_, NQ_, S_ - OBS_, OBS_ * HQ_ * 64);

  // 7) importance pipeline
  obs_kernel<<<HKV_ * OBS_, 256, 0, stream>>>(qobs, kvf, wobs);
  imp_kernel<<<(HKV_ * S_ + 255) / 256, 256, 0, stream>>>(wobs, impv);
  radix_init<<<1, 64, 0, stream>>>(prefix, kneed);
  for (int pass = 0; pass < 4; ++pass) {
    hipMemsetAsync(hist, 0, 4096, stream);
    radix_hist<<<(NC_ + 255) / 256, 256, 0, stream>>>(impv, prefix, pass, hist);
    radix_scan<<<1, 64, 0, stream>>>(hist, prefix, kneed, pass, thr);
  }

  // 8) sparsify + V-transpose + attention + out projection
  sparsify_kernel<<<S_ * HKV_, 128, 0, stream>>>(kvf, impv, thr, ksp, vsp, eb);
  vtrans_kernel<<<dim3(S_ / 64, HKV_), 256, 0, stream>>>(vsp, vspT);
  attn_kernel<<<512, 256, 0, stream>>>(qb16, ksp, vspT, eb, ob16);
  gemm_bt<0><<<dim3(HID_ / 128, S_ / 128), 256, 0, stream>>>(ob16, nullptr, woT, nullptr, out, S_, HID_, HID_);
}